// Round 5
// baseline (148.483 us; speedup 1.0000x reference)
//
#include <hip/hip_runtime.h>
#include <cstdint>
#include <cmath>

#define IN_FEATURES 1024
#define OUT_FEATURES 1024
#define NUM_GMM 5
#define ROWS ((IN_FEATURES + 1) * OUT_FEATURES)   // 1049600 = 4100*256

struct U2 { uint32_t a, b; };

__host__ __device__ constexpr uint32_t rotl32c(uint32_t x, int d) {
  return (x << d) | (x >> (32 - d));
}

// Exact JAX threefry2x32 (20 rounds, 5 key injections)
#define TF_ROUND(r) { x0 += x1; x1 = rotl32c(x1, (r)); x1 ^= x0; }
__host__ __device__ constexpr U2 threefry2x32(uint32_t k0, uint32_t k1,
                                              uint32_t x0, uint32_t x1) {
  const uint32_t ks0 = k0, ks1 = k1, ks2 = k0 ^ k1 ^ 0x1BD11BDAu;
  x0 += ks0; x1 += ks1;
  TF_ROUND(13) TF_ROUND(15) TF_ROUND(26) TF_ROUND(6)
  x0 += ks1; x1 += ks2 + 1u;
  TF_ROUND(17) TF_ROUND(29) TF_ROUND(16) TF_ROUND(24)
  x0 += ks2; x1 += ks0 + 2u;
  TF_ROUND(13) TF_ROUND(15) TF_ROUND(26) TF_ROUND(6)
  x0 += ks0; x1 += ks1 + 3u;
  TF_ROUND(17) TF_ROUND(29) TF_ROUND(16) TF_ROUND(24)
  x0 += ks1; x1 += ks2 + 4u;
  TF_ROUND(13) TF_ROUND(15) TF_ROUND(26) TF_ROUND(6)
  x0 += ks2; x1 += ks0 + 5u;
  return U2{x0, x1};
}

// jax_threefry_partitionable=True (verified R2)
constexpr U2 KC = threefry2x32(0u, 42u, 0u, 0u);   // kcat
constexpr U2 KN = threefry2x32(0u, 42u, 0u, 1u);   // knorm
constexpr uint32_t KCAT0  = KC.a;
constexpr uint32_t KCAT1  = KC.b;
constexpr uint32_t KNORM0 = KN.a;
constexpr uint32_t KNORM1 = KN.b;

__device__ inline float u01_from_bits(uint32_t bits) {
  return __uint_as_float((bits >> 9) | 0x3F800000u) - 1.0f;
}

// f64-lite log: rcp_f32 seed + 2 Newton steps replaces IEEE f64 divide.
// Total err ~1e-16 rel -> f32 result correctly rounded (argmax-safe).
__device__ inline float log_f32_acc(float x) {
  uint32_t ix = __float_as_uint(x);
  int e = (int)(ix >> 23) - 127;
  float mf = __uint_as_float((ix & 0x007FFFFFu) | 0x3F800000u); // [1,2)
  if (mf > 1.4142135381698608f) { mf *= 0.5f; e += 1; }         // (0.707,1.414]
  double m = (double)mf;
  double d = m + 1.0;                               // [1.707, 2.414]
  double r = (double)__builtin_amdgcn_rcpf((float)d);
  r = r * (2.0 - d * r);                            // Newton 1: ~1e-12
  r = r * (2.0 - d * r);                            // Newton 2: ~1e-16
  double t = (m - 1.0) * r;                         // |t| <= 0.1716
  double t2 = t * t;
  double p = 1.0 / 15.0;
  p = fma(p, t2, 1.0 / 13.0);
  p = fma(p, t2, 1.0 / 11.0);
  p = fma(p, t2, 1.0 / 9.0);
  p = fma(p, t2, 1.0 / 7.0);
  p = fma(p, t2, 1.0 / 5.0);
  p = fma(p, t2, 1.0 / 3.0);
  p = fma(p, t2, 1.0);
  double res = fma((double)e, 0.693147180559945309417, 2.0 * t * p);
  return (float)res;
}

__device__ inline float gumbel_from_bits(uint32_t bits) {
  float f = u01_from_bits(bits);
  float u = fmaxf(1.17549435e-38f, f + 1.17549435e-38f);
  float t1 = log_f32_acc(u);
  float t2 = log_f32_acc(-t1);
  return -t2;
}

// XLA ErfInv f32 (Giles) — smooth path
__device__ inline float erfinv_xla(float x) {
  float w = -log1pf(-x * x);
  float p;
  if (w < 5.0f) {
    w = w - 2.5f;
    p = 2.81022636e-08f;
    p = fmaf(p, w, 3.43273939e-07f);
    p = fmaf(p, w, -3.5233877e-06f);
    p = fmaf(p, w, -4.39150654e-06f);
    p = fmaf(p, w, 0.00021858087f);
    p = fmaf(p, w, -0.00125372503f);
    p = fmaf(p, w, -0.00417768164f);
    p = fmaf(p, w, 0.246640727f);
    p = fmaf(p, w, 1.50140941f);
  } else {
    w = sqrtf(w) - 3.0f;
    p = -0.000200214257f;
    p = fmaf(p, w, 0.000100950558f);
    p = fmaf(p, w, 0.00134934322f);
    p = fmaf(p, w, -0.00367342844f);
    p = fmaf(p, w, 0.00573950773f);
    p = fmaf(p, w, -0.0076224613f);
    p = fmaf(p, w, 0.00943887047f);
    p = fmaf(p, w, 1.00167406f);
    p = fmaf(p, w, 2.83297682f);
  }
  return p * x;
}

__device__ inline float normal_from_bits(uint32_t bits) {
  float f = u01_from_bits(bits);
  const float lo = -0.99999994f;
  float u = fmaxf(lo, f * 2.0f + lo);
  return 1.4142135623730951f * erfinv_xla(u);
}

__device__ inline unsigned short f32_to_bf16_rne(float f) {
  uint32_t u = __float_as_uint(f);
  return (unsigned short)((u + 0x7FFFu + ((u >> 16) & 1u)) >> 16);
}

// Fused: sample weight_bias row r (all threads) + convert 8 x floats (first
// 524288 threads). Memory-bound convert overlaps VALU-bound sampling.
__global__ __launch_bounds__(256) void prep_kernel(
    const float* __restrict__ mean, const float* __restrict__ logstd,
    const float* __restrict__ weight, const float* __restrict__ x,
    unsigned short* __restrict__ wh, float* __restrict__ bias_f32,
    unsigned short* __restrict__ xh, int n_chunks) {
  const int r = blockIdx.x * 256 + threadIdx.x;   // grid covers ROWS exactly

  // ---- x conversion (independent work, overlaps) ----
  if (r < n_chunks) {
    int i = r * 8;
    float4 a = *(const float4*)(x + i);
    float4 b = *(const float4*)(x + i + 4);
    union { unsigned short s[8]; uint4 v; } o;
    o.s[0] = f32_to_bf16_rne(a.x); o.s[1] = f32_to_bf16_rne(a.y);
    o.s[2] = f32_to_bf16_rne(a.z); o.s[3] = f32_to_bf16_rne(a.w);
    o.s[4] = f32_to_bf16_rne(b.x); o.s[5] = f32_to_bf16_rne(b.y);
    o.s[6] = f32_to_bf16_rne(b.z); o.s[7] = f32_to_bf16_rne(b.w);
    *(uint4*)(xh + i) = o.v;
  }

  // ---- GMM sampling ----
  const float* wrow = weight + (size_t)r * NUM_GMM;
  int idx = 0;
  float best = -3.402823466e+38f;
#pragma unroll
  for (int g = 0; g < NUM_GMM; ++g) {
    U2 t = threefry2x32(KCAT0, KCAT1, 0u, (uint32_t)(r * NUM_GMM + g));
    float v = gumbel_from_bits(t.a ^ t.b) + wrow[g];
    if (v > best) { best = v; idx = g; }   // strict >: first-max (jnp.argmax)
  }

  U2 tn = threefry2x32(KNORM0, KNORM1, 0u, (uint32_t)r);
  float eps = normal_from_bits(tn.a ^ tn.b);

  float m = mean[(size_t)r * NUM_GMM + idx];
  float l = logstd[(size_t)r * NUM_GMM + idx];
  // fast tanh/exp: sd = exp(3*tanh(l)); rel err ~1e-6 (negligible vs bf16)
  float e2 = __expf(2.0f * l);
  float th = 1.0f - 2.0f * __builtin_amdgcn_rcpf(e2 + 1.0f);
  float sd = __expf(3.0f * th);
  float wbv = m + sd * eps;
  wh[r] = f32_to_bf16_rne(wbv);
  if (r < OUT_FEATURES) bias_f32[r] = wbv;
}

// ---------------- MFMA GEMM: out[M,1024] = xh @ W'^T + bias ----------------
typedef __attribute__((ext_vector_type(8))) short bf16x8;
typedef __attribute__((ext_vector_type(4))) float f32x4;

#define GBM 128
#define GBN 64
#define GBK 64

__device__ inline void load_lds16(const void* g, void* l) {
  __builtin_amdgcn_global_load_lds(
      (const __attribute__((address_space(1))) unsigned int*)g,
      (__attribute__((address_space(3))) unsigned int*)l, 16, 0, 0);
}

// LDS slot layout (16B slots): slot = ((blk*2 + ksub)*4 + kchunk)*16 + mrow.
// Staging thread t -> slots t, t+256, ... (lane-linear: wave base + lane*16).
// Fragment read for 16x16x32 MFMA: lane L -> slot (blk*2+ksub)*64 + L, i.e.
// ds_read_b128 at base + 16*L: conflict-free (m97 pattern).
//
// Block swizzle: dispatch maps linear block i -> XCD (i&7) [m09 heuristic].
// We assign XCD k the y-tiles [4k, 4k+4) across all 16 x-tiles, so each
// XCD's resident blocks touch 4 A-tiles (1 MB) + whole wh (2.1 MB) < 4 MB
// per-XCD L2 -> A/B stream from L2, not L3 (~200 MB L3 traffic -> ~25 MB).
__global__ __launch_bounds__(256) void gemm_mfma_kernel(
    const unsigned short* __restrict__ xh, const unsigned short* __restrict__ wh,
    const float* __restrict__ bias, float* __restrict__ out) {
  __shared__ unsigned short As[2][GBM * GBK];   // 2 x 16 KB
  __shared__ unsigned short Bs[2][GBN * GBK];   // 2 x 8 KB

  const unsigned short* W = wh + OUT_FEATURES;
  const int tid = threadIdx.x;
  const int w = tid >> 6;
  const int L = tid & 63;

  const int nbx = OUT_FEATURES / GBN;   // 16
  int bi = blockIdx.x;
  int bx, by;
  if (gridDim.x == 512) {               // M=4096 fast path: XCD-aware swizzle
    int xcd = bi & 7;
    int j = bi >> 3;                    // 0..63
    by = xcd * 4 + (j >> 4);            // 4 y-tiles per XCD
    bx = j & 15;
  } else {
    bx = bi % nbx;
    by = bi / nbx;
  }
  const int m_tile = by * GBM;
  const int n_tile = bx * GBN;

  // staging decomposition of slot index t
  const int sm = tid & 15;           // row within 16-block
  const int sh = (tid >> 4) & 3;     // k-chunk (8 elems)
  const int sk = (tid >> 6) & 1;     // k-subtile (0/1)
  const int sb = tid >> 7;           // block base (0/1)
  const int kofs = sk * 32 + sh * 8;

  const unsigned short* gA[4];
  const unsigned short* gB[2];
#pragma unroll
  for (int i = 0; i < 4; ++i)
    gA[i] = xh + (size_t)(m_tile + (2 * i + sb) * 16 + sm) * IN_FEATURES + kofs;
#pragma unroll
  for (int i = 0; i < 2; ++i)
    gB[i] = W + (size_t)(n_tile + (2 * i + sb) * 16 + sm) * IN_FEATURES + kofs;

  f32x4 acc[2][4];
#pragma unroll
  for (int a = 0; a < 2; ++a)
#pragma unroll
    for (int b = 0; b < 4; ++b) acc[a][b] = (f32x4){0.f, 0.f, 0.f, 0.f};

#define STAGE(buf, k0)                                                    \
  {                                                                       \
    _Pragma("unroll")                                                     \
    for (int i = 0; i < 4; ++i)                                           \
      load_lds16(gA[i] + (k0), &As[buf][(size_t)(tid + 256 * i) * 8]);    \
    _Pragma("unroll")                                                     \
    for (int i = 0; i < 2; ++i)                                           \
      load_lds16(gB[i] + (k0), &Bs[buf][(size_t)(tid + 256 * i) * 8]);    \
  }

  STAGE(0, 0)

  const int NK = IN_FEATURES / GBK;   // 16
  for (int kt = 0; kt < NK; ++kt) {
    __syncthreads();                  // drains vmcnt -> stage kt complete
    if (kt + 1 < NK) STAGE((kt + 1) & 1, (kt + 1) * GBK)
    const unsigned short* Ab = As[kt & 1];
    const unsigned short* Bb = Bs[kt & 1];
#pragma unroll
    for (int s = 0; s < 2; ++s) {
      bf16x8 a0 = *(const bf16x8*)(Ab + (((2 * w + 0) * 2 + s) * 64 + L) * 8);
      bf16x8 a1 = *(const bf16x8*)(Ab + (((2 * w + 1) * 2 + s) * 64 + L) * 8);
      bf16x8 b0 = *(const bf16x8*)(Bb + ((0 * 2 + s) * 64 + L) * 8);
      bf16x8 b1 = *(const bf16x8*)(Bb + ((1 * 2 + s) * 64 + L) * 8);
      bf16x8 b2 = *(const bf16x8*)(Bb + ((2 * 2 + s) * 64 + L) * 8);
      bf16x8 b3 = *(const bf16x8*)(Bb + ((3 * 2 + s) * 64 + L) * 8);
      acc[0][0] = __builtin_amdgcn_mfma_f32_16x16x32_bf16(a0, b0, acc[0][0], 0, 0, 0);
      acc[0][1] = __builtin_amdgcn_mfma_f32_16x16x32_bf16(a0, b1, acc[0][1], 0, 0, 0);
      acc[0][2] = __builtin_amdgcn_mfma_f32_16x16x32_bf16(a0, b2, acc[0][2], 0, 0, 0);
      acc[0][3] = __builtin_amdgcn_mfma_f32_16x16x32_bf16(a0, b3, acc[0][3], 0, 0, 0);
      acc[1][0] = __builtin_amdgcn_mfma_f32_16x16x32_bf16(a1, b0, acc[1][0], 0, 0, 0);
      acc[1][1] = __builtin_amdgcn_mfma_f32_16x16x32_bf16(a1, b1, acc[1][1], 0, 0, 0);
      acc[1][2] = __builtin_amdgcn_mfma_f32_16x16x32_bf16(a1, b2, acc[1][2], 0, 0, 0);
      acc[1][3] = __builtin_amdgcn_mfma_f32_16x16x32_bf16(a1, b3, acc[1][3], 0, 0, 0);
    }
  }

  // Epilogue: C/D layout col = L&15, row = (L>>4)*4 + reg (m89-verified)
  const int colL = L & 15;
  const int rowq = (L >> 4) * 4;
  float bv[4];
#pragma unroll
  for (int nb = 0; nb < 4; ++nb) bv[nb] = bias[n_tile + nb * 16 + colL];
#pragma unroll
  for (int bm = 0; bm < 2; ++bm) {
#pragma unroll
    for (int reg = 0; reg < 4; ++reg) {
      int row = m_tile + w * 32 + bm * 16 + rowq + reg;
#pragma unroll
      for (int nb = 0; nb < 4; ++nb) {
        out[(size_t)row * OUT_FEATURES + n_tile + nb * 16 + colL] =
            acc[bm][nb][reg] + bv[nb];
      }
    }
  }
}

extern "C" void kernel_launch(void* const* d_in, const int* in_sizes, int n_in,
                              void* d_out, int out_size, void* d_ws, size_t ws_size,
                              hipStream_t stream) {
  const float* x      = (const float*)d_in[0];
  const float* mean   = (const float*)d_in[1];
  const float* logstd = (const float*)d_in[2];
  const float* weight = (const float*)d_in[3];
  float* out = (float*)d_out;

  const int M = in_sizes[0] / IN_FEATURES;   // 4096

  // ws layout: xh bf16 [M*1024] | wh bf16 [ROWS] | bias f32 [1024]
  unsigned short* xh = (unsigned short*)d_ws;
  unsigned short* wh = (unsigned short*)((char*)d_ws + (size_t)M * IN_FEATURES * 2);
  float* biasf = (float*)((char*)wh + (size_t)ROWS * 2);

  const int n_chunks = M * IN_FEATURES / 8;
  prep_kernel<<<ROWS / 256, 256, 0, stream>>>(
      mean, logstd, weight, x, wh, biasf, xh, n_chunks);

  const int nblocks = (OUT_FEATURES / GBN) * (M / GBM);   // 512 at M=4096
  gemm_mfma_kernel<<<nblocks, 256, 0, stream>>>(xh, wh, biasf, out);
}

// Round 6
// 138.679 us; speedup vs baseline: 1.0707x; 1.0707x over previous
//
#include <hip/hip_runtime.h>
#include <cstdint>
#include <cmath>

#define IN_FEATURES 1024
#define OUT_FEATURES 1024
#define NUM_GMM 5
#define ROWS ((IN_FEATURES + 1) * OUT_FEATURES)   // 1049600 = 4100*256

struct U2 { uint32_t a, b; };

__host__ __device__ constexpr uint32_t rotl32c(uint32_t x, int d) {
  return (x << d) | (x >> (32 - d));
}

// Exact JAX threefry2x32 (20 rounds, 5 key injections)
#define TF_ROUND(r) { x0 += x1; x1 = rotl32c(x1, (r)); x1 ^= x0; }
__host__ __device__ constexpr U2 threefry2x32(uint32_t k0, uint32_t k1,
                                              uint32_t x0, uint32_t x1) {
  const uint32_t ks0 = k0, ks1 = k1, ks2 = k0 ^ k1 ^ 0x1BD11BDAu;
  x0 += ks0; x1 += ks1;
  TF_ROUND(13) TF_ROUND(15) TF_ROUND(26) TF_ROUND(6)
  x0 += ks1; x1 += ks2 + 1u;
  TF_ROUND(17) TF_ROUND(29) TF_ROUND(16) TF_ROUND(24)
  x0 += ks2; x1 += ks0 + 2u;
  TF_ROUND(13) TF_ROUND(15) TF_ROUND(26) TF_ROUND(6)
  x0 += ks0; x1 += ks1 + 3u;
  TF_ROUND(17) TF_ROUND(29) TF_ROUND(16) TF_ROUND(24)
  x0 += ks1; x1 += ks2 + 4u;
  TF_ROUND(13) TF_ROUND(15) TF_ROUND(26) TF_ROUND(6)
  x0 += ks2; x1 += ks0 + 5u;
  return U2{x0, x1};
}

// jax_threefry_partitionable=True (verified R2)
constexpr U2 KC = threefry2x32(0u, 42u, 0u, 0u);   // kcat
constexpr U2 KN = threefry2x32(0u, 42u, 0u, 1u);   // knorm
constexpr uint32_t KCAT0  = KC.a;
constexpr uint32_t KCAT1  = KC.b;
constexpr uint32_t KNORM0 = KN.a;
constexpr uint32_t KNORM1 = KN.b;

__device__ inline float u01_from_bits(uint32_t bits) {
  return __uint_as_float((bits >> 9) | 0x3F800000u) - 1.0f;
}

// CR-grade f64-lite log (err ~4e-15 rel -> f32 result correctly rounded).
// Only executed on near-tie fallback rows (~0.01%).
__device__ inline float log_f32_acc(float x) {
  uint32_t ix = __float_as_uint(x);
  int e = (int)(ix >> 23) - 127;
  float mf = __uint_as_float((ix & 0x007FFFFFu) | 0x3F800000u); // [1,2)
  if (mf > 1.4142135381698608f) { mf *= 0.5f; e += 1; }         // (0.707,1.414]
  double m = (double)mf;
  double d = m + 1.0;                               // [1.707, 2.414]
  double r = (double)__builtin_amdgcn_rcpf((float)d);
  r = r * (2.0 - d * r);                            // Newton 1: ~1e-12
  r = r * (2.0 - d * r);                            // Newton 2: ~1e-16
  double t = (m - 1.0) * r;                         // |t| <= 0.1716
  double t2 = t * t;
  double p = 1.0 / 15.0;
  p = fma(p, t2, 1.0 / 13.0);
  p = fma(p, t2, 1.0 / 11.0);
  p = fma(p, t2, 1.0 / 9.0);
  p = fma(p, t2, 1.0 / 7.0);
  p = fma(p, t2, 1.0 / 5.0);
  p = fma(p, t2, 1.0 / 3.0);
  p = fma(p, t2, 1.0);
  double res = fma((double)e, 0.693147180559945309417, 2.0 * t * p);
  return (float)res;
}

__device__ inline float u_from_bits_clamped(uint32_t bits) {
  float f = u01_from_bits(bits);
  return fmaxf(1.17549435e-38f, f + 1.17549435e-38f);
}

// Accurate gumbel (CR f32 chain) — fallback path only
__device__ inline float gumbel_acc(uint32_t bits) {
  float u = u_from_bits_clamped(bits);
  float t1 = log_f32_acc(u);
  float t2 = log_f32_acc(-t1);
  return -t2;
}

// Cheap gumbel: hw v_log_f32. abs err <= ~8e-6; values only feed argmax,
// near-ties (margin < 1e-3) re-resolved with gumbel_acc.
__device__ inline float gumbel_fast(uint32_t bits) {
  float u = u_from_bits_clamped(bits);
  float t1 = __logf(u);          // < 0
  return -__logf(-t1);
}

// XLA ErfInv f32 (Giles). log1p(-x^2) -> -log((1-x)(1+x)): cancellation-safe
// (1-x exact by Sterbenz for x>=0.5), hw log ok (smooth path, value-accuracy).
__device__ inline float erfinv_xla(float x) {
  float s = (1.0f - x) * (1.0f + x);
  float w = -__logf(s);
  float p;
  if (w < 5.0f) {
    w = w - 2.5f;
    p = 2.81022636e-08f;
    p = fmaf(p, w, 3.43273939e-07f);
    p = fmaf(p, w, -3.5233877e-06f);
    p = fmaf(p, w, -4.39150654e-06f);
    p = fmaf(p, w, 0.00021858087f);
    p = fmaf(p, w, -0.00125372503f);
    p = fmaf(p, w, -0.00417768164f);
    p = fmaf(p, w, 0.246640727f);
    p = fmaf(p, w, 1.50140941f);
  } else {
    w = sqrtf(w) - 3.0f;
    p = -0.000200214257f;
    p = fmaf(p, w, 0.000100950558f);
    p = fmaf(p, w, 0.00134934322f);
    p = fmaf(p, w, -0.00367342844f);
    p = fmaf(p, w, 0.00573950773f);
    p = fmaf(p, w, -0.0076224613f);
    p = fmaf(p, w, 0.00943887047f);
    p = fmaf(p, w, 1.00167406f);
    p = fmaf(p, w, 2.83297682f);
  }
  return p * x;
}

__device__ inline float normal_from_bits(uint32_t bits) {
  float f = u01_from_bits(bits);
  const float lo = -0.99999994f;
  float u = fmaxf(lo, f * 2.0f + lo);
  return 1.4142135623730951f * erfinv_xla(u);
}

__device__ inline unsigned short f32_to_bf16_rne(float f) {
  uint32_t u = __float_as_uint(f);
  return (unsigned short)((u + 0x7FFFu + ((u >> 16) & 1u)) >> 16);
}

// Fused: sample weight_bias row r (all threads) + convert 8 x floats (first
// 524288 threads). Memory-bound convert overlaps VALU-bound sampling.
__global__ __launch_bounds__(256) void prep_kernel(
    const float* __restrict__ mean, const float* __restrict__ logstd,
    const float* __restrict__ weight, const float* __restrict__ x,
    unsigned short* __restrict__ wh, float* __restrict__ bias_f32,
    unsigned short* __restrict__ xh, int n_chunks) {
  const int r = blockIdx.x * 256 + threadIdx.x;   // grid covers ROWS exactly

  // ---- x conversion (independent work, overlaps) ----
  if (r < n_chunks) {
    int i = r * 8;
    float4 a = *(const float4*)(x + i);
    float4 b = *(const float4*)(x + i + 4);
    union { unsigned short s[8]; uint4 v; } o;
    o.s[0] = f32_to_bf16_rne(a.x); o.s[1] = f32_to_bf16_rne(a.y);
    o.s[2] = f32_to_bf16_rne(a.z); o.s[3] = f32_to_bf16_rne(a.w);
    o.s[4] = f32_to_bf16_rne(b.x); o.s[5] = f32_to_bf16_rne(b.y);
    o.s[6] = f32_to_bf16_rne(b.z); o.s[7] = f32_to_bf16_rne(b.w);
    *(uint4*)(xh + i) = o.v;
  }

  // ---- GMM sampling ----
  const float* wrow = weight + (size_t)r * NUM_GMM;
  uint32_t bits[NUM_GMM];
  float wv[NUM_GMM];
  float v[NUM_GMM];
#pragma unroll
  for (int g = 0; g < NUM_GMM; ++g) {
    U2 t = threefry2x32(KCAT0, KCAT1, 0u, (uint32_t)(r * NUM_GMM + g));
    bits[g] = t.a ^ t.b;
    wv[g] = wrow[g];
    v[g] = gumbel_fast(bits[g]) + wv[g];
  }
  int idx = 0;
  float best = v[0], second = -3.402823466e+38f;
#pragma unroll
  for (int g = 1; g < NUM_GMM; ++g) {
    if (v[g] > best) { second = best; best = v[g]; idx = g; }
    else if (v[g] > second) { second = v[g]; }
  }
  if (best - second < 1e-3f) {      // near-tie: re-resolve with CR chain
    idx = 0;
    best = -3.402823466e+38f;
#pragma unroll
    for (int g = 0; g < NUM_GMM; ++g) {
      float va = gumbel_acc(bits[g]) + wv[g];
      if (va > best) { best = va; idx = g; }   // strict >: first-max (argmax)
    }
  }

  U2 tn = threefry2x32(KNORM0, KNORM1, 0u, (uint32_t)r);
  float eps = normal_from_bits(tn.a ^ tn.b);

  float m = mean[(size_t)r * NUM_GMM + idx];
  float l = logstd[(size_t)r * NUM_GMM + idx];
  // fast tanh/exp: sd = exp(3*tanh(l)); rel err ~1e-6 (negligible vs bf16)
  float e2 = __expf(2.0f * l);
  float th = 1.0f - 2.0f * __builtin_amdgcn_rcpf(e2 + 1.0f);
  float sd = __expf(3.0f * th);
  float wbv = m + sd * eps;
  wh[r] = f32_to_bf16_rne(wbv);
  if (r < OUT_FEATURES) bias_f32[r] = wbv;
}

// ---------------- MFMA GEMM: out[M,1024] = xh @ W'^T + bias ----------------
typedef __attribute__((ext_vector_type(8))) short bf16x8;
typedef __attribute__((ext_vector_type(4))) float f32x4;

#define GBM 128
#define GBN 64
#define GBK 64

__device__ inline void load_lds16(const void* g, void* l) {
  __builtin_amdgcn_global_load_lds(
      (const __attribute__((address_space(1))) unsigned int*)g,
      (__attribute__((address_space(3))) unsigned int*)l, 16, 0, 0);
}

// LDS slot layout (16B slots): slot = ((blk*2 + ksub)*4 + kchunk)*16 + mrow.
// Staging thread t -> slots t, t+256, ... (lane-linear: wave base + lane*16).
// Fragment read for 16x16x32 MFMA: lane L -> slot (blk*2+ksub)*64 + L, i.e.
// ds_read_b128 at base + 16*L: conflict-free (m97 pattern).
// NOTE: R5's XCD swizzle REGRESSED (148.5 vs 144.9) — GEMM is latency-bound,
// not L3-BW-bound. Linear 2D mapping restored.
__global__ __launch_bounds__(256) void gemm_mfma_kernel(
    const unsigned short* __restrict__ xh, const unsigned short* __restrict__ wh,
    const float* __restrict__ bias, float* __restrict__ out) {
  __shared__ unsigned short As[2][GBM * GBK];   // 2 x 16 KB
  __shared__ unsigned short Bs[2][GBN * GBK];   // 2 x 8 KB

  const unsigned short* W = wh + OUT_FEATURES;
  const int tid = threadIdx.x;
  const int w = tid >> 6;
  const int L = tid & 63;

  const int m_tile = blockIdx.y * GBM;
  const int n_tile = blockIdx.x * GBN;

  // staging decomposition of slot index t
  const int sm = tid & 15;           // row within 16-block
  const int sh = (tid >> 4) & 3;     // k-chunk (8 elems)
  const int sk = (tid >> 6) & 1;     // k-subtile (0/1)
  const int sb = tid >> 7;           // block base (0/1)
  const int kofs = sk * 32 + sh * 8;

  const unsigned short* gA[4];
  const unsigned short* gB[2];
#pragma unroll
  for (int i = 0; i < 4; ++i)
    gA[i] = xh + (size_t)(m_tile + (2 * i + sb) * 16 + sm) * IN_FEATURES + kofs;
#pragma unroll
  for (int i = 0; i < 2; ++i)
    gB[i] = W + (size_t)(n_tile + (2 * i + sb) * 16 + sm) * IN_FEATURES + kofs;

  f32x4 acc[2][4];
#pragma unroll
  for (int a = 0; a < 2; ++a)
#pragma unroll
    for (int b = 0; b < 4; ++b) acc[a][b] = (f32x4){0.f, 0.f, 0.f, 0.f};

#define STAGE(buf, k0)                                                    \
  {                                                                       \
    _Pragma("unroll")                                                     \
    for (int i = 0; i < 4; ++i)                                           \
      load_lds16(gA[i] + (k0), &As[buf][(size_t)(tid + 256 * i) * 8]);    \
    _Pragma("unroll")                                                     \
    for (int i = 0; i < 2; ++i)                                           \
      load_lds16(gB[i] + (k0), &Bs[buf][(size_t)(tid + 256 * i) * 8]);    \
  }

  STAGE(0, 0)

  const int NK = IN_FEATURES / GBK;   // 16
  for (int kt = 0; kt < NK; ++kt) {
    __syncthreads();                  // drains vmcnt -> stage kt complete
    if (kt + 1 < NK) STAGE((kt + 1) & 1, (kt + 1) * GBK)
    const unsigned short* Ab = As[kt & 1];
    const unsigned short* Bb = Bs[kt & 1];
#pragma unroll
    for (int s = 0; s < 2; ++s) {
      bf16x8 a0 = *(const bf16x8*)(Ab + (((2 * w + 0) * 2 + s) * 64 + L) * 8);
      bf16x8 a1 = *(const bf16x8*)(Ab + (((2 * w + 1) * 2 + s) * 64 + L) * 8);
      bf16x8 b0 = *(const bf16x8*)(Bb + ((0 * 2 + s) * 64 + L) * 8);
      bf16x8 b1 = *(const bf16x8*)(Bb + ((1 * 2 + s) * 64 + L) * 8);
      bf16x8 b2 = *(const bf16x8*)(Bb + ((2 * 2 + s) * 64 + L) * 8);
      bf16x8 b3 = *(const bf16x8*)(Bb + ((3 * 2 + s) * 64 + L) * 8);
      acc[0][0] = __builtin_amdgcn_mfma_f32_16x16x32_bf16(a0, b0, acc[0][0], 0, 0, 0);
      acc[0][1] = __builtin_amdgcn_mfma_f32_16x16x32_bf16(a0, b1, acc[0][1], 0, 0, 0);
      acc[0][2] = __builtin_amdgcn_mfma_f32_16x16x32_bf16(a0, b2, acc[0][2], 0, 0, 0);
      acc[0][3] = __builtin_amdgcn_mfma_f32_16x16x32_bf16(a0, b3, acc[0][3], 0, 0, 0);
      acc[1][0] = __builtin_amdgcn_mfma_f32_16x16x32_bf16(a1, b0, acc[1][0], 0, 0, 0);
      acc[1][1] = __builtin_amdgcn_mfma_f32_16x16x32_bf16(a1, b1, acc[1][1], 0, 0, 0);
      acc[1][2] = __builtin_amdgcn_mfma_f32_16x16x32_bf16(a1, b2, acc[1][2], 0, 0, 0);
      acc[1][3] = __builtin_amdgcn_mfma_f32_16x16x32_bf16(a1, b3, acc[1][3], 0, 0, 0);
    }
  }

  // Epilogue: C/D layout col = L&15, row = (L>>4)*4 + reg (m89-verified)
  const int colL = L & 15;
  const int rowq = (L >> 4) * 4;
  float bv[4];
#pragma unroll
  for (int nb = 0; nb < 4; ++nb) bv[nb] = bias[n_tile + nb * 16 + colL];
#pragma unroll
  for (int bm = 0; bm < 2; ++bm) {
#pragma unroll
    for (int reg = 0; reg < 4; ++reg) {
      int row = m_tile + w * 32 + bm * 16 + rowq + reg;
#pragma unroll
      for (int nb = 0; nb < 4; ++nb) {
        out[(size_t)row * OUT_FEATURES + n_tile + nb * 16 + colL] =
            acc[bm][nb][reg] + bv[nb];
      }
    }
  }
}

extern "C" void kernel_launch(void* const* d_in, const int* in_sizes, int n_in,
                              void* d_out, int out_size, void* d_ws, size_t ws_size,
                              hipStream_t stream) {
  const float* x      = (const float*)d_in[0];
  const float* mean   = (const float*)d_in[1];
  const float* logstd = (const float*)d_in[2];
  const float* weight = (const float*)d_in[3];
  float* out = (float*)d_out;

  const int M = in_sizes[0] / IN_FEATURES;   // 4096

  // ws layout: xh bf16 [M*1024] | wh bf16 [ROWS] | bias f32 [1024]
  unsigned short* xh = (unsigned short*)d_ws;
  unsigned short* wh = (unsigned short*)((char*)d_ws + (size_t)M * IN_FEATURES * 2);
  float* biasf = (float*)((char*)wh + (size_t)ROWS * 2);

  const int n_chunks = M * IN_FEATURES / 8;
  prep_kernel<<<ROWS / 256, 256, 0, stream>>>(
      mean, logstd, weight, x, wh, biasf, xh, n_chunks);

  dim3 grid(OUT_FEATURES / GBN, M / GBM);
  gemm_mfma_kernel<<<grid, 256, 0, stream>>>(xh, wh, biasf, out);
}

// Round 7
// 137.362 us; speedup vs baseline: 1.0810x; 1.0096x over previous
//
#include <hip/hip_runtime.h>
#include <cstdint>
#include <cmath>

#define IN_FEATURES 1024
#define OUT_FEATURES 1024
#define NUM_GMM 5
#define ROWS ((IN_FEATURES + 1) * OUT_FEATURES)   // 1049600 = 4100*256

struct U2 { uint32_t a, b; };

__host__ __device__ constexpr uint32_t rotl32c(uint32_t x, int d) {
  return (x << d) | (x >> (32 - d));
}

// Exact JAX threefry2x32 (20 rounds, 5 key injections)
#define TF_ROUND(r) { x0 += x1; x1 = rotl32c(x1, (r)); x1 ^= x0; }
__host__ __device__ constexpr U2 threefry2x32(uint32_t k0, uint32_t k1,
                                              uint32_t x0, uint32_t x1) {
  const uint32_t ks0 = k0, ks1 = k1, ks2 = k0 ^ k1 ^ 0x1BD11BDAu;
  x0 += ks0; x1 += ks1;
  TF_ROUND(13) TF_ROUND(15) TF_ROUND(26) TF_ROUND(6)
  x0 += ks1; x1 += ks2 + 1u;
  TF_ROUND(17) TF_ROUND(29) TF_ROUND(16) TF_ROUND(24)
  x0 += ks2; x1 += ks0 + 2u;
  TF_ROUND(13) TF_ROUND(15) TF_ROUND(26) TF_ROUND(6)
  x0 += ks0; x1 += ks1 + 3u;
  TF_ROUND(17) TF_ROUND(29) TF_ROUND(16) TF_ROUND(24)
  x0 += ks1; x1 += ks2 + 4u;
  TF_ROUND(13) TF_ROUND(15) TF_ROUND(26) TF_ROUND(6)
  x0 += ks2; x1 += ks0 + 5u;
  return U2{x0, x1};
}

// jax_threefry_partitionable=True (verified R2)
constexpr U2 KC = threefry2x32(0u, 42u, 0u, 0u);   // kcat
constexpr U2 KN = threefry2x32(0u, 42u, 0u, 1u);   // knorm
constexpr uint32_t KCAT0  = KC.a;
constexpr uint32_t KCAT1  = KC.b;
constexpr uint32_t KNORM0 = KN.a;
constexpr uint32_t KNORM1 = KN.b;

__device__ inline float u01_from_bits(uint32_t bits) {
  return __uint_as_float((bits >> 9) | 0x3F800000u) - 1.0f;
}

// CR-grade f64-lite log (err ~4e-15 rel -> f32 result correctly rounded).
// Only executed on near-tie fallback rows (~0.05%).
__device__ inline float log_f32_acc(float x) {
  uint32_t ix = __float_as_uint(x);
  int e = (int)(ix >> 23) - 127;
  float mf = __uint_as_float((ix & 0x007FFFFFu) | 0x3F800000u); // [1,2)
  if (mf > 1.4142135381698608f) { mf *= 0.5f; e += 1; }         // (0.707,1.414]
  double m = (double)mf;
  double d = m + 1.0;                               // [1.707, 2.414]
  double r = (double)__builtin_amdgcn_rcpf((float)d);
  r = r * (2.0 - d * r);                            // Newton 1: ~1e-12
  r = r * (2.0 - d * r);                            // Newton 2: ~1e-16
  double t = (m - 1.0) * r;                         // |t| <= 0.1716
  double t2 = t * t;
  double p = 1.0 / 15.0;
  p = fma(p, t2, 1.0 / 13.0);
  p = fma(p, t2, 1.0 / 11.0);
  p = fma(p, t2, 1.0 / 9.0);
  p = fma(p, t2, 1.0 / 7.0);
  p = fma(p, t2, 1.0 / 5.0);
  p = fma(p, t2, 1.0 / 3.0);
  p = fma(p, t2, 1.0);
  double res = fma((double)e, 0.693147180559945309417, 2.0 * t * p);
  return (float)res;
}

__device__ inline float u_from_bits_clamped(uint32_t bits) {
  float f = u01_from_bits(bits);
  return fmaxf(1.17549435e-38f, f + 1.17549435e-38f);
}

// Accurate gumbel (CR f32 chain) — fallback path only
__device__ inline float gumbel_acc(uint32_t bits) {
  float u = u_from_bits_clamped(bits);
  float t1 = log_f32_acc(u);
  float t2 = log_f32_acc(-t1);
  return -t2;
}

// Cheap gumbel: hw v_log_f32. abs err <= ~8e-6; values only feed argmax,
// near-ties (margin < 1e-3) re-resolved with gumbel_acc.
__device__ inline float gumbel_fast(uint32_t bits) {
  float u = u_from_bits_clamped(bits);
  float t1 = __logf(u);          // < 0
  return -__logf(-t1);
}

// XLA ErfInv f32 (Giles). log1p(-x^2) -> -log((1-x)(1+x)): cancellation-safe
// (1-x exact by Sterbenz for x>=0.5), hw log ok (smooth path, value-accuracy).
__device__ inline float erfinv_xla(float x) {
  float s = (1.0f - x) * (1.0f + x);
  float w = -__logf(s);
  float p;
  if (w < 5.0f) {
    w = w - 2.5f;
    p = 2.81022636e-08f;
    p = fmaf(p, w, 3.43273939e-07f);
    p = fmaf(p, w, -3.5233877e-06f);
    p = fmaf(p, w, -4.39150654e-06f);
    p = fmaf(p, w, 0.00021858087f);
    p = fmaf(p, w, -0.00125372503f);
    p = fmaf(p, w, -0.00417768164f);
    p = fmaf(p, w, 0.246640727f);
    p = fmaf(p, w, 1.50140941f);
  } else {
    w = sqrtf(w) - 3.0f;
    p = -0.000200214257f;
    p = fmaf(p, w, 0.000100950558f);
    p = fmaf(p, w, 0.00134934322f);
    p = fmaf(p, w, -0.00367342844f);
    p = fmaf(p, w, 0.00573950773f);
    p = fmaf(p, w, -0.0076224613f);
    p = fmaf(p, w, 0.00943887047f);
    p = fmaf(p, w, 1.00167406f);
    p = fmaf(p, w, 2.83297682f);
  }
  return p * x;
}

__device__ inline float normal_from_bits(uint32_t bits) {
  float f = u01_from_bits(bits);
  const float lo = -0.99999994f;
  float u = fmaxf(lo, f * 2.0f + lo);
  return 1.4142135623730951f * erfinv_xla(u);
}

__device__ inline unsigned short f32_to_bf16_rne(float f) {
  uint32_t u = __float_as_uint(f);
  return (unsigned short)((u + 0x7FFFu + ((u >> 16) & 1u)) >> 16);
}

// Fused: sample weight_bias row r (all threads) + convert 8 x floats (first
// 524288 threads). Memory-bound convert overlaps VALU-bound sampling.
__global__ __launch_bounds__(256) void prep_kernel(
    const float* __restrict__ mean, const float* __restrict__ logstd,
    const float* __restrict__ weight, const float* __restrict__ x,
    unsigned short* __restrict__ wh, float* __restrict__ bias_f32,
    unsigned short* __restrict__ xh, int n_chunks) {
  const int r = blockIdx.x * 256 + threadIdx.x;   // grid covers ROWS exactly

  // ---- x conversion (independent work, overlaps) ----
  if (r < n_chunks) {
    int i = r * 8;
    float4 a = *(const float4*)(x + i);
    float4 b = *(const float4*)(x + i + 4);
    union { unsigned short s[8]; uint4 v; } o;
    o.s[0] = f32_to_bf16_rne(a.x); o.s[1] = f32_to_bf16_rne(a.y);
    o.s[2] = f32_to_bf16_rne(a.z); o.s[3] = f32_to_bf16_rne(a.w);
    o.s[4] = f32_to_bf16_rne(b.x); o.s[5] = f32_to_bf16_rne(b.y);
    o.s[6] = f32_to_bf16_rne(b.z); o.s[7] = f32_to_bf16_rne(b.w);
    *(uint4*)(xh + i) = o.v;
  }

  // ---- GMM sampling ----
  const float* wrow = weight + (size_t)r * NUM_GMM;
  uint32_t bits[NUM_GMM];
  float wv[NUM_GMM];
  float v[NUM_GMM];
#pragma unroll
  for (int g = 0; g < NUM_GMM; ++g) {
    U2 t = threefry2x32(KCAT0, KCAT1, 0u, (uint32_t)(r * NUM_GMM + g));
    bits[g] = t.a ^ t.b;
    wv[g] = wrow[g];
    v[g] = gumbel_fast(bits[g]) + wv[g];
  }
  int idx = 0;
  float best = v[0], second = -3.402823466e+38f;
#pragma unroll
  for (int g = 1; g < NUM_GMM; ++g) {
    if (v[g] > best) { second = best; best = v[g]; idx = g; }
    else if (v[g] > second) { second = v[g]; }
  }
  if (__builtin_expect(best - second < 1e-3f, 0)) {  // near-tie: CR re-resolve
    idx = 0;
    best = -3.402823466e+38f;
#pragma unroll
    for (int g = 0; g < NUM_GMM; ++g) {
      float va = gumbel_acc(bits[g]) + wv[g];
      if (va > best) { best = va; idx = g; }   // strict >: first-max (argmax)
    }
  }

  U2 tn = threefry2x32(KNORM0, KNORM1, 0u, (uint32_t)r);
  float eps = normal_from_bits(tn.a ^ tn.b);

  float m = mean[(size_t)r * NUM_GMM + idx];
  float l = logstd[(size_t)r * NUM_GMM + idx];
  // fast tanh/exp: sd = exp(3*tanh(l)); rel err ~1e-6 (negligible vs bf16)
  float e2 = __expf(2.0f * l);
  float th = 1.0f - 2.0f * __builtin_amdgcn_rcpf(e2 + 1.0f);
  float sd = __expf(3.0f * th);
  float wbv = m + sd * eps;
  wh[r] = f32_to_bf16_rne(wbv);
  if (r < OUT_FEATURES) bias_f32[r] = wbv;
}

// ---------------- MFMA GEMM: out[M,1024] = xh @ W'^T + bias ----------------
typedef __attribute__((ext_vector_type(8))) short bf16x8;
typedef __attribute__((ext_vector_type(4))) float f32x4;

#define GBM 128
#define GBN 64
#define GBK 64

__device__ inline void load_lds16(const void* g, void* l) {
  __builtin_amdgcn_global_load_lds(
      (const __attribute__((address_space(1))) unsigned int*)g,
      (__attribute__((address_space(3))) unsigned int*)l, 16, 0, 0);
}

// LDS slot layout (16B slots): slot = ((blk*2 + ksub)*4 + kchunk)*16 + mrow.
// Staging thread t -> slots t, t+256, ... (lane-linear: wave base + lane*16).
// Fragment read: lane L -> ds_read_b128 at base + 16*L: conflict-free.
//
// Pipeline (R7): 3 LDS buffers, raw s_barrier + manual s_waitcnt vmcnt(6).
// __syncthreads() would drain vmcnt(0), killing the in-flight stage kt+1
// every iteration (the m97 ~20% stall). Here each wave waits only for its
// own stage-kt loads (6 outstanding allowed = stage kt+1), raw-barriers,
// then issues stage kt+2 into buf[(kt+2)%3] == buf[(kt-1)%3], whose readers
// are provably past this barrier (their ds_reads drained before their MFMAs
// in iter kt-1). Prefetch depth goes 1 -> 2 full iterations.
__global__ __launch_bounds__(256) void gemm_mfma_kernel(
    const unsigned short* __restrict__ xh, const unsigned short* __restrict__ wh,
    const float* __restrict__ bias, float* __restrict__ out) {
  __shared__ unsigned short As[3][GBM * GBK];   // 3 x 16 KB
  __shared__ unsigned short Bs[3][GBN * GBK];   // 3 x 8 KB  => 72 KB total

  const unsigned short* W = wh + OUT_FEATURES;
  const int tid = threadIdx.x;
  const int w = tid >> 6;
  const int L = tid & 63;

  const int m_tile = blockIdx.y * GBM;
  const int n_tile = blockIdx.x * GBN;

  // staging decomposition of slot index t
  const int sm = tid & 15;           // row within 16-block
  const int sh = (tid >> 4) & 3;     // k-chunk (8 elems)
  const int sk = (tid >> 6) & 1;     // k-subtile (0/1)
  const int sb = tid >> 7;           // block base (0/1)
  const int kofs = sk * 32 + sh * 8;

  const unsigned short* gA[4];
  const unsigned short* gB[2];
#pragma unroll
  for (int i = 0; i < 4; ++i)
    gA[i] = xh + (size_t)(m_tile + (2 * i + sb) * 16 + sm) * IN_FEATURES + kofs;
#pragma unroll
  for (int i = 0; i < 2; ++i)
    gB[i] = W + (size_t)(n_tile + (2 * i + sb) * 16 + sm) * IN_FEATURES + kofs;

  f32x4 acc[2][4];
#pragma unroll
  for (int a = 0; a < 2; ++a)
#pragma unroll
    for (int b = 0; b < 4; ++b) acc[a][b] = (f32x4){0.f, 0.f, 0.f, 0.f};

#define STAGE(buf, k0)                                                    \
  {                                                                       \
    _Pragma("unroll")                                                     \
    for (int i = 0; i < 4; ++i)                                           \
      load_lds16(gA[i] + (k0), &As[buf][(size_t)(tid + 256 * i) * 8]);    \
    _Pragma("unroll")                                                     \
    for (int i = 0; i < 2; ++i)                                           \
      load_lds16(gB[i] + (k0), &Bs[buf][(size_t)(tid + 256 * i) * 8]);    \
  }

  STAGE(0, 0)
  STAGE(1, GBK)

  const int NK = IN_FEATURES / GBK;   // 16
#pragma unroll
  for (int kt = 0; kt < NK; ++kt) {
    // wait for stage kt only (stage kt+1's 6 loads may remain in flight)
    asm volatile("s_waitcnt vmcnt(6)" ::: "memory");
    asm volatile("s_barrier" ::: "memory");
    if (kt + 2 < NK) STAGE((kt + 2) % 3, (kt + 2) * GBK)
    const unsigned short* Ab = As[kt % 3];
    const unsigned short* Bb = Bs[kt % 3];
#pragma unroll
    for (int s = 0; s < 2; ++s) {
      bf16x8 a0 = *(const bf16x8*)(Ab + (((2 * w + 0) * 2 + s) * 64 + L) * 8);
      bf16x8 a1 = *(const bf16x8*)(Ab + (((2 * w + 1) * 2 + s) * 64 + L) * 8);
      bf16x8 b0 = *(const bf16x8*)(Bb + ((0 * 2 + s) * 64 + L) * 8);
      bf16x8 b1 = *(const bf16x8*)(Bb + ((1 * 2 + s) * 64 + L) * 8);
      bf16x8 b2 = *(const bf16x8*)(Bb + ((2 * 2 + s) * 64 + L) * 8);
      bf16x8 b3 = *(const bf16x8*)(Bb + ((3 * 2 + s) * 64 + L) * 8);
      acc[0][0] = __builtin_amdgcn_mfma_f32_16x16x32_bf16(a0, b0, acc[0][0], 0, 0, 0);
      acc[0][1] = __builtin_amdgcn_mfma_f32_16x16x32_bf16(a0, b1, acc[0][1], 0, 0, 0);
      acc[0][2] = __builtin_amdgcn_mfma_f32_16x16x32_bf16(a0, b2, acc[0][2], 0, 0, 0);
      acc[0][3] = __builtin_amdgcn_mfma_f32_16x16x32_bf16(a0, b3, acc[0][3], 0, 0, 0);
      acc[1][0] = __builtin_amdgcn_mfma_f32_16x16x32_bf16(a1, b0, acc[1][0], 0, 0, 0);
      acc[1][1] = __builtin_amdgcn_mfma_f32_16x16x32_bf16(a1, b1, acc[1][1], 0, 0, 0);
      acc[1][2] = __builtin_amdgcn_mfma_f32_16x16x32_bf16(a1, b2, acc[1][2], 0, 0, 0);
      acc[1][3] = __builtin_amdgcn_mfma_f32_16x16x32_bf16(a1, b3, acc[1][3], 0, 0, 0);
    }
  }

  // Epilogue: C/D layout col = L&15, row = (L>>4)*4 + reg (m89-verified)
  const int colL = L & 15;
  const int rowq = (L >> 4) * 4;
  float bv[4];
#pragma unroll
  for (int nb = 0; nb < 4; ++nb) bv[nb] = bias[n_tile + nb * 16 + colL];
#pragma unroll
  for (int bm = 0; bm < 2; ++bm) {
#pragma unroll
    for (int reg = 0; reg < 4; ++reg) {
      int row = m_tile + w * 32 + bm * 16 + rowq + reg;
#pragma unroll
      for (int nb = 0; nb < 4; ++nb) {
        out[(size_t)row * OUT_FEATURES + n_tile + nb * 16 + colL] =
            acc[bm][nb][reg] + bv[nb];
      }
    }
  }
}

extern "C" void kernel_launch(void* const* d_in, const int* in_sizes, int n_in,
                              void* d_out, int out_size, void* d_ws, size_t ws_size,
                              hipStream_t stream) {
  const float* x      = (const float*)d_in[0];
  const float* mean   = (const float*)d_in[1];
  const float* logstd = (const float*)d_in[2];
  const float* weight = (const float*)d_in[3];
  float* out = (float*)d_out;

  const int M = in_sizes[0] / IN_FEATURES;   // 4096

  // ws layout: xh bf16 [M*1024] | wh bf16 [ROWS] | bias f32 [1024]
  unsigned short* xh = (unsigned short*)d_ws;
  unsigned short* wh = (unsigned short*)((char*)d_ws + (size_t)M * IN_FEATURES * 2);
  float* biasf = (float*)((char*)wh + (size_t)ROWS * 2);

  const int n_chunks = M * IN_FEATURES / 8;
  prep_kernel<<<ROWS / 256, 256, 0, stream>>>(
      mean, logstd, weight, x, wh, biasf, xh, n_chunks);

  dim3 grid(OUT_FEATURES / GBN, M / GBM);
  gemm_mfma_kernel<<<grid, 256, 0, stream>>>(xh, wh, biasf, out);
}